// Round 1
// baseline (1032.047 us; speedup 1.0000x reference)
//
#include <hip/hip_runtime.h>

#define NN 100000   // nodes
#define NE 1600000  // edges
#define NG 512      // graphs
// IN=128, HID=128, OUT=64

// ---------- degree histogram ----------
__global__ void k_hist(const int* __restrict__ dst, int* __restrict__ deg) {
    int i = blockIdx.x * blockDim.x + threadIdx.x;
    int stride = gridDim.x * blockDim.x;
    for (; i < NE; i += stride) atomicAdd(&deg[dst[i]], 1);
}

// ---------- dinv = rsqrt(in_deg + 1)  (self loop) ----------
__global__ void k_dinv(const int* __restrict__ deg, float* __restrict__ dinv) {
    int i = blockIdx.x * blockDim.x + threadIdx.x;
    if (i < NN) dinv[i] = rsqrtf((float)(deg[i] + 1));
}

// ---------- exclusive scan of deg -> offs[NN+1], cur (single block) ----------
__global__ __launch_bounds__(1024) void k_scan(const int* __restrict__ deg,
                                               int* __restrict__ offs,
                                               int* __restrict__ cur) {
    __shared__ int part[1024];
    int t = threadIdx.x;
    const int chunk = (NN + 1023) / 1024;
    int beg = t * chunk;
    int end = beg + chunk; if (end > NN) end = NN;
    int s = 0;
    for (int i = beg; i < end; ++i) s += deg[i];
    part[t] = s;
    __syncthreads();
    for (int d = 1; d < 1024; d <<= 1) {
        int v = (t >= d) ? part[t - d] : 0;
        __syncthreads();
        part[t] += v;
        __syncthreads();
    }
    int run = part[t] - s;  // exclusive base
    for (int i = beg; i < end; ++i) {
        offs[i] = run; cur[i] = run; run += deg[i];
    }
    if (t == 1023) offs[NN] = part[1023];
}

// ---------- scatter edges into CSR by dst ----------
__global__ void k_scatter(const int* __restrict__ src, const int* __restrict__ dst,
                          int* __restrict__ cur, int* __restrict__ csr) {
    int i = blockIdx.x * blockDim.x + threadIdx.x;
    int stride = gridDim.x * blockDim.x;
    for (; i < NE; i += stride) {
        int d = dst[i];
        int pos = atomicAdd(&cur[d], 1);
        csr[pos] = src[i];
    }
}

// ---------- fused G = dinv ⊙ (X @ W), X is [NN,128], W is [128,FOUT] ----------
// 32 rows per block; W + 32-row X tile staged in LDS; 4x4 (or 2x4) register tile.
template <int FOUT>
__global__ __launch_bounds__(256) void k_mm_scale(const float* __restrict__ X,
                                                  const float* __restrict__ W,
                                                  const float* __restrict__ dinv,
                                                  float* __restrict__ Out) {
    constexpr int NCG = FOUT / 4;   // col groups of 4
    constexpr int NRG = 256 / NCG;  // row groups
    constexpr int RT  = 32 / NRG;   // rows per thread (4 for FOUT=128, 2 for 64)
    __shared__ float Ws[128 * FOUT];
    __shared__ float Xs[32 * 128];
    int t = threadIdx.x;
    {
        const float4* Wg = (const float4*)W;
        float4* Ws4 = (float4*)Ws;
        for (int i = t; i < 128 * FOUT / 4; i += 256) Ws4[i] = Wg[i];
        const float4* Xg = (const float4*)(X + (size_t)blockIdx.x * 32 * 128);
        float4* Xs4 = (float4*)Xs;
        for (int i = t; i < 32 * 32; i += 256) Xs4[i] = Xg[i];
    }
    __syncthreads();
    int cg = t % NCG;
    int rg = t / NCG;
    float acc[RT][4];
#pragma unroll
    for (int r = 0; r < RT; ++r) { acc[r][0] = acc[r][1] = acc[r][2] = acc[r][3] = 0.f; }
    for (int k = 0; k < 128; k += 4) {
        float4 xv[RT];
#pragma unroll
        for (int r = 0; r < RT; ++r)
            xv[r] = *(const float4*)&Xs[(rg * RT + r) * 128 + k];
#pragma unroll
        for (int j = 0; j < 4; ++j) {
            float4 w = *(const float4*)&Ws[(k + j) * FOUT + 4 * cg];
#pragma unroll
            for (int r = 0; r < RT; ++r) {
                float xb = (j == 0) ? xv[r].x : (j == 1) ? xv[r].y
                         : (j == 2) ? xv[r].z : xv[r].w;
                acc[r][0] += xb * w.x; acc[r][1] += xb * w.y;
                acc[r][2] += xb * w.z; acc[r][3] += xb * w.w;
            }
        }
    }
    int row0 = blockIdx.x * 32 + rg * RT;
#pragma unroll
    for (int r = 0; r < RT; ++r) {
        int row = row0 + r;
        float di = dinv[row];
        float4 o;
        o.x = acc[r][0] * di; o.y = acc[r][1] * di;
        o.z = acc[r][2] * di; o.w = acc[r][3] * di;
        *(float4*)&Out[(size_t)row * FOUT + 4 * cg] = o;
    }
}

// ---------- aggregation, 128 features: one wave per node, float2 per lane ----------
__global__ __launch_bounds__(256) void k_agg_relu128(
    const float* __restrict__ G, const int* __restrict__ csr,
    const int* __restrict__ offs, const float* __restrict__ dinv,
    const float* __restrict__ bias, float* __restrict__ Out) {
    int node = (blockIdx.x * 256 + threadIdx.x) >> 6;
    int lane = threadIdx.x & 63;
    if (node >= NN) return;
    const float2* g = (const float2*)G;
    float2 acc = g[(size_t)node * 64 + lane];  // self loop term (already dinv-scaled)
    int e0 = offs[node], e1 = offs[node + 1];
    for (int e = e0; e < e1; ++e) {
        int s = csr[e];
        float2 v = g[(size_t)s * 64 + lane];
        acc.x += v.x; acc.y += v.y;
    }
    float di = dinv[node];
    float2 b = ((const float2*)bias)[lane];
    float ox = fmaxf(acc.x * di + b.x, 0.f);
    float oy = fmaxf(acc.y * di + b.y, 0.f);
    ((float2*)Out)[(size_t)node * 64 + lane] = make_float2(ox, oy);
}

// ---------- aggregation, 64 features: one wave per node, float per lane ----------
__global__ __launch_bounds__(256) void k_agg64(
    const float* __restrict__ G, const int* __restrict__ csr,
    const int* __restrict__ offs, const float* __restrict__ dinv,
    const float* __restrict__ bias, float* __restrict__ Out) {
    int node = (blockIdx.x * 256 + threadIdx.x) >> 6;
    int lane = threadIdx.x & 63;
    if (node >= NN) return;
    float acc = G[(size_t)node * 64 + lane];
    int e0 = offs[node], e1 = offs[node + 1];
    for (int e = e0; e < e1; ++e) acc += G[(size_t)csr[e] * 64 + lane];
    Out[(size_t)node * 64 + lane] = acc * dinv[node] + bias[lane];
}

// ---------- mean pool: one 64-thread block per graph, batch is sorted ----------
__global__ __launch_bounds__(64) void k_pool(const float* __restrict__ H,
                                             const int* __restrict__ batch,
                                             float* __restrict__ out) {
    int gph = blockIdx.x;
    int lo = 0, hi = NN;
    while (lo < hi) { int m = (lo + hi) >> 1; if (batch[m] < gph) lo = m + 1; else hi = m; }
    int s0 = lo;
    hi = NN;
    while (lo < hi) { int m = (lo + hi) >> 1; if (batch[m] <= gph) lo = m + 1; else hi = m; }
    int s1 = lo;
    int f = threadIdx.x;
    float s = 0.f;
    for (int n = s0; n < s1; ++n) s += H[(size_t)n * 64 + f];
    int cnt = s1 - s0;
    out[gph * 64 + f] = (cnt > 0) ? s / (float)cnt : 0.f;
}

extern "C" void kernel_launch(void* const* d_in, const int* in_sizes, int n_in,
                              void* d_out, int out_size, void* d_ws, size_t ws_size,
                              hipStream_t stream) {
    const float* x     = (const float*)d_in[0];
    const int*   ei    = (const int*)d_in[1];   // [2, NE] int32
    const int*   batch = (const int*)d_in[2];
    const float* W1    = (const float*)d_in[3];
    const float* b1    = (const float*)d_in[4];
    const float* W2    = (const float*)d_in[5];
    const float* b2    = (const float*)d_in[6];
    const int* esrc = ei;
    const int* edst = ei + NE;

    char* ws = (char*)d_ws;
    size_t off = 0;
    float* A    = (float*)(ws + off); off += (size_t)NN * 128 * 4;  // g1, later g2+agg2
    float* B    = (float*)(ws + off); off += (size_t)NN * 128 * 4;  // relu(agg1)
    int*   csr  = (int*)(ws + off);   off += (size_t)NE * 4;
    int*   offs = (int*)(ws + off);   off += ((size_t)NN + 8) * 4;
    int*   cur  = (int*)(ws + off);   off += (size_t)NN * 4;
    int*   deg  = (int*)(ws + off);   off += (size_t)NN * 4;
    float* dinv = (float*)(ws + off); off += (size_t)NN * 4;
    // total ~110.4 MB

    float* G2   = A;                      // [NN,64]
    float* AGG2 = A + (size_t)NN * 64;    // [NN,64]

    hipMemsetAsync(deg, 0, NN * sizeof(int), stream);
    k_hist<<<2048, 256, 0, stream>>>(edst, deg);
    k_dinv<<<(NN + 255) / 256, 256, 0, stream>>>(deg, dinv);
    k_scan<<<1, 1024, 0, stream>>>(deg, offs, cur);
    k_scatter<<<2048, 256, 0, stream>>>(esrc, edst, cur, csr);

    // layer 1: g1 = dinv ⊙ (x @ W1);  B = relu(dinv ⊙ csr_sum(g1) + b1)
    k_mm_scale<128><<<NN / 32, 256, 0, stream>>>(x, W1, dinv, A);
    k_agg_relu128<<<(NN + 3) / 4, 256, 0, stream>>>(A, csr, offs, dinv, b1, B);

    // layer 2: g2 = dinv ⊙ (B @ W2);  agg2 = dinv ⊙ csr_sum(g2) + b2
    k_mm_scale<64><<<NN / 32, 256, 0, stream>>>(B, W2, dinv, G2);
    k_agg64<<<(NN + 3) / 4, 256, 0, stream>>>(G2, csr, offs, dinv, b2, AGG2);

    // pool
    k_pool<<<NG, 64, 0, stream>>>(AGG2, batch, (float*)d_out);
}

// Round 2
// 819.177 us; speedup vs baseline: 1.2599x; 1.2599x over previous
//
#include <hip/hip_runtime.h>

#define NN 100000   // nodes
#define NE 1600000  // edges
#define NG 512      // graphs
#define NBLK 391    // ceil(NN/256) scan blocks
// IN=128, HID=128, OUT=64

// ---------- degree histogram ----------
__global__ void k_hist(const int* __restrict__ dst, int* __restrict__ deg) {
    int i = blockIdx.x * blockDim.x + threadIdx.x;
    int stride = gridDim.x * blockDim.x;
    for (; i < NE; i += stride) atomicAdd(&deg[dst[i]], 1);
}

// ---------- dinv = rsqrt(in_deg + 1)  (self loop) ----------
__global__ void k_dinv(const int* __restrict__ deg, float* __restrict__ dinv) {
    int i = blockIdx.x * blockDim.x + threadIdx.x;
    if (i < NN) dinv[i] = rsqrtf((float)(deg[i] + 1));
}

// ---------- 3-phase exclusive scan of deg -> offs[NN+1], cur ----------
__global__ __launch_bounds__(256) void k_bsum(const int* __restrict__ deg,
                                              int* __restrict__ bsum) {
    __shared__ int red[256];
    int t = threadIdx.x;
    int i = blockIdx.x * 256 + t;
    red[t] = (i < NN) ? deg[i] : 0;
    __syncthreads();
    for (int d = 128; d > 0; d >>= 1) {
        if (t < d) red[t] += red[t + d];
        __syncthreads();
    }
    if (t == 0) bsum[blockIdx.x] = red[0];
}

__global__ __launch_bounds__(512) void k_bscan(const int* __restrict__ bsum,
                                               int* __restrict__ bbase) {
    __shared__ int s[512];
    int t = threadIdx.x;
    int v = (t < NBLK) ? bsum[t] : 0;
    s[t] = v;
    __syncthreads();
    for (int d = 1; d < 512; d <<= 1) {
        int u = (t >= d) ? s[t - d] : 0;
        __syncthreads();
        s[t] += u;
        __syncthreads();
    }
    if (t < NBLK) bbase[t] = s[t] - v;  // exclusive base per block
}

__global__ __launch_bounds__(256) void k_chunkscan(const int* __restrict__ deg,
                                                   const int* __restrict__ bbase,
                                                   int* __restrict__ offs,
                                                   int* __restrict__ cur) {
    __shared__ int s[256];
    int t = threadIdx.x;
    int i = blockIdx.x * 256 + t;
    int v = (i < NN) ? deg[i] : 0;
    s[t] = v;
    __syncthreads();
    for (int d = 1; d < 256; d <<= 1) {
        int u = (t >= d) ? s[t - d] : 0;
        __syncthreads();
        s[t] += u;
        __syncthreads();
    }
    if (i < NN) {
        int ex = bbase[blockIdx.x] + s[t] - v;
        offs[i] = ex;
        cur[i] = ex;
    }
    if (i == 0) offs[NN] = NE;  // sum of in-degrees == edge count, exactly
}

// ---------- scatter edges into CSR by dst ----------
__global__ void k_scatter(const int* __restrict__ src, const int* __restrict__ dst,
                          int* __restrict__ cur, int* __restrict__ csr) {
    int i = blockIdx.x * blockDim.x + threadIdx.x;
    int stride = gridDim.x * blockDim.x;
    for (; i < NE; i += stride) {
        int d = dst[i];
        int pos = atomicAdd(&cur[d], 1);
        csr[pos] = src[i];
    }
}

// ---------- fused G = dinv ⊙ (X @ W), X is [NN,128], W is [128,FOUT] ----------
// 32 rows per block; W + 32-row X tile staged in LDS; register tile per thread.
template <int FOUT>
__global__ __launch_bounds__(256) void k_mm_scale(const float* __restrict__ X,
                                                  const float* __restrict__ W,
                                                  const float* __restrict__ dinv,
                                                  float* __restrict__ Out) {
    constexpr int NCG = FOUT / 4;   // col groups of 4
    constexpr int NRG = 256 / NCG;  // row groups
    constexpr int RT  = 32 / NRG;   // rows per thread (4 for FOUT=128, 2 for 64)
    __shared__ float Ws[128 * FOUT];
    __shared__ float Xs[32 * 128];
    int t = threadIdx.x;
    {
        const float4* Wg = (const float4*)W;
        float4* Ws4 = (float4*)Ws;
        for (int i = t; i < 128 * FOUT / 4; i += 256) Ws4[i] = Wg[i];
        const float4* Xg = (const float4*)(X + (size_t)blockIdx.x * 32 * 128);
        float4* Xs4 = (float4*)Xs;
        for (int i = t; i < 32 * 32; i += 256) Xs4[i] = Xg[i];
    }
    __syncthreads();
    int cg = t % NCG;
    int rg = t / NCG;
    float acc[RT][4];
#pragma unroll
    for (int r = 0; r < RT; ++r) { acc[r][0] = acc[r][1] = acc[r][2] = acc[r][3] = 0.f; }
    for (int k = 0; k < 128; k += 4) {
        float4 xv[RT];
#pragma unroll
        for (int r = 0; r < RT; ++r)
            xv[r] = *(const float4*)&Xs[(rg * RT + r) * 128 + k];
#pragma unroll
        for (int j = 0; j < 4; ++j) {
            float4 w = *(const float4*)&Ws[(k + j) * FOUT + 4 * cg];
#pragma unroll
            for (int r = 0; r < RT; ++r) {
                float xb = (j == 0) ? xv[r].x : (j == 1) ? xv[r].y
                         : (j == 2) ? xv[r].z : xv[r].w;
                acc[r][0] += xb * w.x; acc[r][1] += xb * w.y;
                acc[r][2] += xb * w.z; acc[r][3] += xb * w.w;
            }
        }
    }
    int row0 = blockIdx.x * 32 + rg * RT;
#pragma unroll
    for (int r = 0; r < RT; ++r) {
        int row = row0 + r;
        float di = dinv[row];
        float4 o;
        o.x = acc[r][0] * di; o.y = acc[r][1] * di;
        o.z = acc[r][2] * di; o.w = acc[r][3] * di;
        *(float4*)&Out[(size_t)row * FOUT + 4 * cg] = o;
    }
}

// ---------- aggregation, 128 features: one wave per node, float2 per lane ----------
__global__ __launch_bounds__(256) void k_agg_relu128(
    const float* __restrict__ G, const int* __restrict__ csr,
    const int* __restrict__ offs, const float* __restrict__ dinv,
    const float* __restrict__ bias, float* __restrict__ Out) {
    int node = (blockIdx.x * 256 + threadIdx.x) >> 6;
    int lane = threadIdx.x & 63;
    if (node >= NN) return;
    const float2* g = (const float2*)G;
    float2 acc = g[(size_t)node * 64 + lane];  // self loop term (already dinv-scaled)
    int e0 = offs[node], e1 = offs[node + 1];
    for (int e = e0; e < e1; ++e) {
        int s = csr[e];
        float2 v = g[(size_t)s * 64 + lane];
        acc.x += v.x; acc.y += v.y;
    }
    float di = dinv[node];
    float2 b = ((const float2*)bias)[lane];
    float ox = fmaxf(acc.x * di + b.x, 0.f);
    float oy = fmaxf(acc.y * di + b.y, 0.f);
    ((float2*)Out)[(size_t)node * 64 + lane] = make_float2(ox, oy);
}

// ---------- aggregation, 64 features: one wave per node, float per lane ----------
__global__ __launch_bounds__(256) void k_agg64(
    const float* __restrict__ G, const int* __restrict__ csr,
    const int* __restrict__ offs, const float* __restrict__ dinv,
    const float* __restrict__ bias, float* __restrict__ Out) {
    int node = (blockIdx.x * 256 + threadIdx.x) >> 6;
    int lane = threadIdx.x & 63;
    if (node >= NN) return;
    float acc = G[(size_t)node * 64 + lane];
    int e0 = offs[node], e1 = offs[node + 1];
    for (int e = e0; e < e1; ++e) acc += G[(size_t)csr[e] * 64 + lane];
    Out[(size_t)node * 64 + lane] = acc * dinv[node] + bias[lane];
}

// ---------- mean pool: one 64-thread block per graph, batch is sorted ----------
__global__ __launch_bounds__(64) void k_pool(const float* __restrict__ H,
                                             const int* __restrict__ batch,
                                             float* __restrict__ out) {
    int gph = blockIdx.x;
    int lo = 0, hi = NN;
    while (lo < hi) { int m = (lo + hi) >> 1; if (batch[m] < gph) lo = m + 1; else hi = m; }
    int s0 = lo;
    hi = NN;
    while (lo < hi) { int m = (lo + hi) >> 1; if (batch[m] <= gph) lo = m + 1; else hi = m; }
    int s1 = lo;
    int f = threadIdx.x;
    float s = 0.f;
    for (int n = s0; n < s1; ++n) s += H[(size_t)n * 64 + f];
    int cnt = s1 - s0;
    out[gph * 64 + f] = (cnt > 0) ? s / (float)cnt : 0.f;
}

extern "C" void kernel_launch(void* const* d_in, const int* in_sizes, int n_in,
                              void* d_out, int out_size, void* d_ws, size_t ws_size,
                              hipStream_t stream) {
    const float* x     = (const float*)d_in[0];
    const int*   ei    = (const int*)d_in[1];   // [2, NE] int32
    const int*   batch = (const int*)d_in[2];
    const float* W1    = (const float*)d_in[3];
    const float* b1    = (const float*)d_in[4];
    const float* W2    = (const float*)d_in[5];
    const float* b2    = (const float*)d_in[6];
    const int* esrc = ei;
    const int* edst = ei + NE;

    char* ws = (char*)d_ws;
    size_t off = 0;
    float* A    = (float*)(ws + off); off += (size_t)NN * 128 * 4;  // g1, later g2+agg2
    float* B    = (float*)(ws + off); off += (size_t)NN * 128 * 4;  // relu(agg1)
    int*   csr  = (int*)(ws + off);   off += (size_t)NE * 4;
    int*   offs = (int*)(ws + off);   off += ((size_t)NN + 8) * 4;
    int*   cur  = (int*)(ws + off);   off += (size_t)NN * 4;
    int*   deg  = (int*)(ws + off);   off += (size_t)NN * 4;
    float* dinv = (float*)(ws + off); off += (size_t)NN * 4;
    int*   bsum = (int*)(ws + off);   off += 512 * 4;
    int*   bbase= (int*)(ws + off);   off += 512 * 4;
    // total ~110.4 MB

    float* G2   = A;                      // [NN,64]
    float* AGG2 = A + (size_t)NN * 64;    // [NN,64]

    hipMemsetAsync(deg, 0, NN * sizeof(int), stream);
    k_hist<<<2048, 256, 0, stream>>>(edst, deg);
    k_dinv<<<(NN + 255) / 256, 256, 0, stream>>>(deg, dinv);

    // 3-phase parallel exclusive scan (replaces 232 µs single-block scan)
    k_bsum<<<NBLK, 256, 0, stream>>>(deg, bsum);
    k_bscan<<<1, 512, 0, stream>>>(bsum, bbase);
    k_chunkscan<<<NBLK, 256, 0, stream>>>(deg, bbase, offs, cur);

    k_scatter<<<2048, 256, 0, stream>>>(esrc, edst, cur, csr);

    // layer 1: g1 = dinv ⊙ (x @ W1);  B = relu(dinv ⊙ csr_sum(g1) + b1)
    k_mm_scale<128><<<NN / 32, 256, 0, stream>>>(x, W1, dinv, A);
    k_agg_relu128<<<(NN + 3) / 4, 256, 0, stream>>>(A, csr, offs, dinv, b1, B);

    // layer 2: g2 = dinv ⊙ (B @ W2);  agg2 = dinv ⊙ csr_sum(g2) + b2
    k_mm_scale<64><<<NN / 32, 256, 0, stream>>>(B, W2, dinv, G2);
    k_agg64<<<(NN + 3) / 4, 256, 0, stream>>>(G2, csr, offs, dinv, b2, AGG2);

    // pool
    k_pool<<<NG, 64, 0, stream>>>(AGG2, batch, (float*)d_out);
}

// Round 3
// 652.637 us; speedup vs baseline: 1.5813x; 1.2552x over previous
//
#include <hip/hip_runtime.h>
#include <hip/hip_fp16.h>

#define NN 100000   // nodes
#define NE 1600000  // edges
#define NG 512      // graphs
#define NBLK 391    // ceil(NN/256) scan blocks
// IN=128, HID=128, OUT=64

// ---------- degree histogram ----------
__global__ void k_hist(const int* __restrict__ dst, int* __restrict__ deg) {
    int i = blockIdx.x * blockDim.x + threadIdx.x;
    int stride = gridDim.x * blockDim.x;
    for (; i < NE; i += stride) atomicAdd(&deg[dst[i]], 1);
}

// ---------- dinv = rsqrt(in_deg + 1)  (self loop) ----------
__global__ void k_dinv(const int* __restrict__ deg, float* __restrict__ dinv) {
    int i = blockIdx.x * blockDim.x + threadIdx.x;
    if (i < NN) dinv[i] = rsqrtf((float)(deg[i] + 1));
}

// ---------- 3-phase exclusive scan of deg -> offs[NN+1], cur ----------
__global__ __launch_bounds__(256) void k_bsum(const int* __restrict__ deg,
                                              int* __restrict__ bsum) {
    __shared__ int red[256];
    int t = threadIdx.x;
    int i = blockIdx.x * 256 + t;
    red[t] = (i < NN) ? deg[i] : 0;
    __syncthreads();
    for (int d = 128; d > 0; d >>= 1) {
        if (t < d) red[t] += red[t + d];
        __syncthreads();
    }
    if (t == 0) bsum[blockIdx.x] = red[0];
}

__global__ __launch_bounds__(512) void k_bscan(const int* __restrict__ bsum,
                                               int* __restrict__ bbase) {
    __shared__ int s[512];
    int t = threadIdx.x;
    int v = (t < NBLK) ? bsum[t] : 0;
    s[t] = v;
    __syncthreads();
    for (int d = 1; d < 512; d <<= 1) {
        int u = (t >= d) ? s[t - d] : 0;
        __syncthreads();
        s[t] += u;
        __syncthreads();
    }
    if (t < NBLK) bbase[t] = s[t] - v;  // exclusive base per block
}

__global__ __launch_bounds__(256) void k_chunkscan(const int* __restrict__ deg,
                                                   const int* __restrict__ bbase,
                                                   int* __restrict__ offs,
                                                   int* __restrict__ cur) {
    __shared__ int s[256];
    int t = threadIdx.x;
    int i = blockIdx.x * 256 + t;
    int v = (i < NN) ? deg[i] : 0;
    s[t] = v;
    __syncthreads();
    for (int d = 1; d < 256; d <<= 1) {
        int u = (t >= d) ? s[t - d] : 0;
        __syncthreads();
        s[t] += u;
        __syncthreads();
    }
    if (i < NN) {
        int ex = bbase[blockIdx.x] + s[t] - v;
        offs[i] = ex;
        cur[i] = ex;
    }
    if (i == 0) offs[NN] = NE;  // sum of in-degrees == edge count, exactly
}

// ---------- scatter edges into CSR by dst ----------
__global__ void k_scatter(const int* __restrict__ src, const int* __restrict__ dst,
                          int* __restrict__ cur, int* __restrict__ csr) {
    int i = blockIdx.x * blockDim.x + threadIdx.x;
    int stride = gridDim.x * blockDim.x;
    for (; i < NE; i += stride) {
        int d = dst[i];
        int pos = atomicAdd(&cur[d], 1);
        csr[pos] = src[i];
    }
}

// ---------- fused G = fp16( dinv ⊙ (X @ W) ), X fp32 [NN,128], W [128,FOUT] ----------
// 32 rows per block; W + 32-row X tile staged in LDS; register tile per thread.
template <int FOUT>
__global__ __launch_bounds__(256) void k_mm_scale(const float* __restrict__ X,
                                                  const float* __restrict__ W,
                                                  const float* __restrict__ dinv,
                                                  __half* __restrict__ Out) {
    constexpr int NCG = FOUT / 4;   // col groups of 4
    constexpr int NRG = 256 / NCG;  // row groups
    constexpr int RT  = 32 / NRG;   // rows per thread (4 for FOUT=128, 2 for 64)
    __shared__ float Ws[128 * FOUT];
    __shared__ float Xs[32 * 128];
    int t = threadIdx.x;
    {
        const float4* Wg = (const float4*)W;
        float4* Ws4 = (float4*)Ws;
        for (int i = t; i < 128 * FOUT / 4; i += 256) Ws4[i] = Wg[i];
        const float4* Xg = (const float4*)(X + (size_t)blockIdx.x * 32 * 128);
        float4* Xs4 = (float4*)Xs;
        for (int i = t; i < 32 * 32; i += 256) Xs4[i] = Xg[i];
    }
    __syncthreads();
    int cg = t % NCG;
    int rg = t / NCG;
    float acc[RT][4];
#pragma unroll
    for (int r = 0; r < RT; ++r) { acc[r][0] = acc[r][1] = acc[r][2] = acc[r][3] = 0.f; }
    for (int k = 0; k < 128; k += 4) {
        float4 xv[RT];
#pragma unroll
        for (int r = 0; r < RT; ++r)
            xv[r] = *(const float4*)&Xs[(rg * RT + r) * 128 + k];
#pragma unroll
        for (int j = 0; j < 4; ++j) {
            float4 w = *(const float4*)&Ws[(k + j) * FOUT + 4 * cg];
#pragma unroll
            for (int r = 0; r < RT; ++r) {
                float xb = (j == 0) ? xv[r].x : (j == 1) ? xv[r].y
                         : (j == 2) ? xv[r].z : xv[r].w;
                acc[r][0] += xb * w.x; acc[r][1] += xb * w.y;
                acc[r][2] += xb * w.z; acc[r][3] += xb * w.w;
            }
        }
    }
    int row0 = blockIdx.x * 32 + rg * RT;
#pragma unroll
    for (int r = 0; r < RT; ++r) {
        int row = row0 + r;
        float di = dinv[row];
        __half2 h0 = __floats2half2_rn(acc[r][0] * di, acc[r][1] * di);
        __half2 h1 = __floats2half2_rn(acc[r][2] * di, acc[r][3] * di);
        __half2* op = (__half2*)(Out + (size_t)row * FOUT + 4 * cg);
        op[0] = h0; op[1] = h1;
    }
}

// ---------- aggregation, 128 fp16 features: one wave per node, half2 per lane ----------
__global__ __launch_bounds__(256) void k_agg_relu128(
    const __half* __restrict__ G, const int* __restrict__ csr,
    const int* __restrict__ offs, const float* __restrict__ dinv,
    const float* __restrict__ bias, float* __restrict__ Out) {
    int node = (blockIdx.x * 256 + threadIdx.x) >> 6;
    int lane = threadIdx.x & 63;
    if (node >= NN) return;
    const __half2* g = (const __half2*)G;  // 64 half2 per row
    float2 a0 = __half22float2(g[(size_t)node * 64 + lane]);  // self loop term
    float2 a1 = make_float2(0.f, 0.f);
    float2 a2 = make_float2(0.f, 0.f);
    float2 a3 = make_float2(0.f, 0.f);
    int e0 = offs[node], e1 = offs[node + 1];
    int e = e0;
    for (; e + 3 < e1; e += 4) {  // 4-way MLP: independent gather chains
        int s0 = csr[e], s1 = csr[e + 1], s2 = csr[e + 2], s3 = csr[e + 3];
        float2 v0 = __half22float2(g[(size_t)s0 * 64 + lane]);
        float2 v1 = __half22float2(g[(size_t)s1 * 64 + lane]);
        float2 v2 = __half22float2(g[(size_t)s2 * 64 + lane]);
        float2 v3 = __half22float2(g[(size_t)s3 * 64 + lane]);
        a0.x += v0.x; a0.y += v0.y;
        a1.x += v1.x; a1.y += v1.y;
        a2.x += v2.x; a2.y += v2.y;
        a3.x += v3.x; a3.y += v3.y;
    }
    for (; e < e1; ++e) {
        float2 v = __half22float2(g[(size_t)csr[e] * 64 + lane]);
        a0.x += v.x; a0.y += v.y;
    }
    float accx = (a0.x + a1.x) + (a2.x + a3.x);
    float accy = (a0.y + a1.y) + (a2.y + a3.y);
    float di = dinv[node];
    float2 b = ((const float2*)bias)[lane];
    float ox = fmaxf(accx * di + b.x, 0.f);
    float oy = fmaxf(accy * di + b.y, 0.f);
    ((float2*)Out)[(size_t)node * 64 + lane] = make_float2(ox, oy);
}

// ---------- aggregation, 64 fp16 features: one wave per node, half per lane ----------
__global__ __launch_bounds__(256) void k_agg64(
    const __half* __restrict__ G, const int* __restrict__ csr,
    const int* __restrict__ offs, const float* __restrict__ dinv,
    const float* __restrict__ bias, float* __restrict__ Out) {
    int node = (blockIdx.x * 256 + threadIdx.x) >> 6;
    int lane = threadIdx.x & 63;
    if (node >= NN) return;
    float a0 = __half2float(G[(size_t)node * 64 + lane]);  // self loop
    float a1 = 0.f, a2 = 0.f, a3 = 0.f;
    int e0 = offs[node], e1 = offs[node + 1];
    int e = e0;
    for (; e + 3 < e1; e += 4) {
        int s0 = csr[e], s1 = csr[e + 1], s2 = csr[e + 2], s3 = csr[e + 3];
        float v0 = __half2float(G[(size_t)s0 * 64 + lane]);
        float v1 = __half2float(G[(size_t)s1 * 64 + lane]);
        float v2 = __half2float(G[(size_t)s2 * 64 + lane]);
        float v3 = __half2float(G[(size_t)s3 * 64 + lane]);
        a0 += v0; a1 += v1; a2 += v2; a3 += v3;
    }
    for (; e < e1; ++e) a0 += __half2float(G[(size_t)csr[e] * 64 + lane]);
    float acc = (a0 + a1) + (a2 + a3);
    Out[(size_t)node * 64 + lane] = acc * dinv[node] + bias[lane];
}

// ---------- mean pool: one 64-thread block per graph, batch is sorted ----------
__global__ __launch_bounds__(64) void k_pool(const float* __restrict__ H,
                                             const int* __restrict__ batch,
                                             float* __restrict__ out) {
    int gph = blockIdx.x;
    int lo = 0, hi = NN;
    while (lo < hi) { int m = (lo + hi) >> 1; if (batch[m] < gph) lo = m + 1; else hi = m; }
    int s0 = lo;
    hi = NN;
    while (lo < hi) { int m = (lo + hi) >> 1; if (batch[m] <= gph) lo = m + 1; else hi = m; }
    int s1 = lo;
    int f = threadIdx.x;
    float s = 0.f;
    for (int n = s0; n < s1; ++n) s += H[(size_t)n * 64 + f];
    int cnt = s1 - s0;
    out[gph * 64 + f] = (cnt > 0) ? s / (float)cnt : 0.f;
}

extern "C" void kernel_launch(void* const* d_in, const int* in_sizes, int n_in,
                              void* d_out, int out_size, void* d_ws, size_t ws_size,
                              hipStream_t stream) {
    const float* x     = (const float*)d_in[0];
    const int*   ei    = (const int*)d_in[1];   // [2, NE] int32
    const int*   batch = (const int*)d_in[2];
    const float* W1    = (const float*)d_in[3];
    const float* b1    = (const float*)d_in[4];
    const float* W2    = (const float*)d_in[5];
    const float* b2    = (const float*)d_in[6];
    const int* esrc = ei;
    const int* edst = ei + NE;

    char* ws = (char*)d_ws;
    size_t off = 0;
    __half* G1  = (__half*)(ws + off); off += (size_t)NN * 128 * 2;  // fp16 g1
    __half* G2  = (__half*)(ws + off); off += (size_t)NN * 64 * 2;   // fp16 g2
    float* B    = (float*)(ws + off);  off += (size_t)NN * 128 * 4;  // relu(agg1) fp32
    float* AGG2 = (float*)(ws + off);  off += (size_t)NN * 64 * 4;   // fp32
    int*   csr  = (int*)(ws + off);    off += (size_t)NE * 4;
    int*   offs = (int*)(ws + off);    off += ((size_t)NN + 8) * 4;
    int*   cur  = (int*)(ws + off);    off += (size_t)NN * 4;
    int*   deg  = (int*)(ws + off);    off += (size_t)NN * 4;
    float* dinv = (float*)(ws + off);  off += (size_t)NN * 4;
    int*   bsum = (int*)(ws + off);    off += 512 * 4;
    int*   bbase= (int*)(ws + off);    off += 512 * 4;

    hipMemsetAsync(deg, 0, NN * sizeof(int), stream);
    k_hist<<<2048, 256, 0, stream>>>(edst, deg);
    k_dinv<<<(NN + 255) / 256, 256, 0, stream>>>(deg, dinv);

    // 3-phase parallel exclusive scan
    k_bsum<<<NBLK, 256, 0, stream>>>(deg, bsum);
    k_bscan<<<1, 512, 0, stream>>>(bsum, bbase);
    k_chunkscan<<<NBLK, 256, 0, stream>>>(deg, bbase, offs, cur);

    k_scatter<<<2048, 256, 0, stream>>>(esrc, edst, cur, csr);

    // layer 1: g1 = fp16(dinv ⊙ (x @ W1));  B = relu(dinv ⊙ csr_sum(g1) + b1)
    k_mm_scale<128><<<NN / 32, 256, 0, stream>>>(x, W1, dinv, G1);
    k_agg_relu128<<<(NN + 3) / 4, 256, 0, stream>>>(G1, csr, offs, dinv, b1, B);

    // layer 2: g2 = fp16(dinv ⊙ (B @ W2));  agg2 = dinv ⊙ csr_sum(g2) + b2
    k_mm_scale<64><<<NN / 32, 256, 0, stream>>>(B, W2, dinv, G2);
    k_agg64<<<(NN + 3) / 4, 256, 0, stream>>>(G2, csr, offs, dinv, b2, AGG2);

    // pool
    k_pool<<<NG, 64, 0, stream>>>(AGG2, batch, (float*)d_out);
}

// Round 4
// 557.251 us; speedup vs baseline: 1.8520x; 1.1712x over previous
//
#include <hip/hip_runtime.h>
#include <hip/hip_fp16.h>

#define NN 100000   // nodes
#define NE 1600000  // edges
#define NG 512      // graphs
#define NBLK 391    // ceil(NN/256) scan blocks
// IN=128, HID=128, OUT=64

typedef _Float16 half8 __attribute__((ext_vector_type(8)));
typedef _Float16 half4v __attribute__((ext_vector_type(4)));
typedef float floatx4 __attribute__((ext_vector_type(4)));

// ---------- degree histogram ----------
__global__ void k_hist(const int* __restrict__ dst, int* __restrict__ deg) {
    int i = blockIdx.x * blockDim.x + threadIdx.x;
    int stride = gridDim.x * blockDim.x;
    for (; i < NE; i += stride) atomicAdd(&deg[dst[i]], 1);
}

// ---------- dinv = rsqrt(in_deg + 1)  (self loop) ----------
__global__ void k_dinv(const int* __restrict__ deg, float* __restrict__ dinv) {
    int i = blockIdx.x * blockDim.x + threadIdx.x;
    if (i < NN) dinv[i] = rsqrtf((float)(deg[i] + 1));
}

// ---------- 3-phase exclusive scan of deg -> offs[NN+1], cur ----------
__global__ __launch_bounds__(256) void k_bsum(const int* __restrict__ deg,
                                              int* __restrict__ bsum) {
    __shared__ int red[256];
    int t = threadIdx.x;
    int i = blockIdx.x * 256 + t;
    red[t] = (i < NN) ? deg[i] : 0;
    __syncthreads();
    for (int d = 128; d > 0; d >>= 1) {
        if (t < d) red[t] += red[t + d];
        __syncthreads();
    }
    if (t == 0) bsum[blockIdx.x] = red[0];
}

__global__ __launch_bounds__(512) void k_bscan(const int* __restrict__ bsum,
                                               int* __restrict__ bbase) {
    __shared__ int s[512];
    int t = threadIdx.x;
    int v = (t < NBLK) ? bsum[t] : 0;
    s[t] = v;
    __syncthreads();
    for (int d = 1; d < 512; d <<= 1) {
        int u = (t >= d) ? s[t - d] : 0;
        __syncthreads();
        s[t] += u;
        __syncthreads();
    }
    if (t < NBLK) bbase[t] = s[t] - v;  // exclusive base per block
}

__global__ __launch_bounds__(256) void k_chunkscan(const int* __restrict__ deg,
                                                   const int* __restrict__ bbase,
                                                   int* __restrict__ offs,
                                                   int* __restrict__ cur) {
    __shared__ int s[256];
    int t = threadIdx.x;
    int i = blockIdx.x * 256 + t;
    int v = (i < NN) ? deg[i] : 0;
    s[t] = v;
    __syncthreads();
    for (int d = 1; d < 256; d <<= 1) {
        int u = (t >= d) ? s[t - d] : 0;
        __syncthreads();
        s[t] += u;
        __syncthreads();
    }
    if (i < NN) {
        int ex = bbase[blockIdx.x] + s[t] - v;
        offs[i] = ex;
        cur[i] = ex;
    }
    if (i == 0) offs[NN] = NE;  // sum of in-degrees == edge count, exactly
}

// ---------- scatter edges into CSR by dst ----------
__global__ void k_scatter(const int* __restrict__ src, const int* __restrict__ dst,
                          int* __restrict__ cur, int* __restrict__ csr) {
    int i = blockIdx.x * blockDim.x + threadIdx.x;
    int stride = gridDim.x * blockDim.x;
    for (; i < NE; i += stride) {
        int d = dst[i];
        int pos = atomicAdd(&cur[d], 1);
        csr[pos] = src[i];
    }
}

// ---------- W [128][FOUT] fp32 -> Wt [FOUT][128] fp16 (transpose+cast) ----------
__global__ void k_wt(const float* __restrict__ W, __half* __restrict__ Wt, int fout) {
    int idx = blockIdx.x * 256 + threadIdx.x;
    if (idx < 128 * fout) {
        int k = idx / fout, n = idx % fout;
        Wt[n * 128 + k] = __float2half(W[idx]);
    }
}

// ---------- MFMA matmul: Out = fp16( dinv ⊙ (X @ W) ), K=128 ----------
// Block = 256 thr = 4 waves; 64 rows/block; wave w: rows [w*16,w*16+16) x all FOUT.
// mfma_f32_16x16x32_f16; A-frag: A[m=lane&15][k=quad*8+j]; B-frag: B[k][n=lane&15],
// k=quad*8+j; C/D: col=lane&15, row=quad*4+reg.  [HW-verified layouts]
template <int FOUT, bool HALF_IN>
__global__ __launch_bounds__(256) void k_mm_mfma(const void* __restrict__ Xv,
                                                 const __half* __restrict__ Wt,
                                                 const float* __restrict__ dinv,
                                                 __half* __restrict__ Out) {
    constexpr int PITCH = 136;  // halves per LDS row (16B-aligned rows, limits conflicts)
    __shared__ _Float16 Xs[64 * PITCH];
    __shared__ _Float16 Ws[FOUT * PITCH];
    int t = threadIdx.x;
    int row0 = blockIdx.x * 64;

    if (HALF_IN) {
        const __half* X = (const __half*)Xv;
        for (int i = t; i < 64 * 16; i += 256) {  // 8-half chunks
            int r = i >> 4, kg = i & 15;
            int row = row0 + r;
            half8 v = {};
            if (row < NN) v = *(const half8*)(X + (size_t)row * 128 + kg * 8);
            *(half8*)(Xs + r * PITCH + kg * 8) = v;
        }
    } else {
        const float* X = (const float*)Xv;
        for (int i = t; i < 64 * 32; i += 256) {  // float4 chunks
            int r = i >> 5, f4 = i & 31;
            int row = row0 + r;
            half4v h = {};
            if (row < NN) {
                float4 v = *(const float4*)(X + (size_t)row * 128 + f4 * 4);
                h[0] = (_Float16)v.x; h[1] = (_Float16)v.y;
                h[2] = (_Float16)v.z; h[3] = (_Float16)v.w;
            }
            *(half4v*)(Xs + r * PITCH + f4 * 4) = h;
        }
    }
    for (int i = t; i < FOUT * 16; i += 256) {  // Wt straight copy (fp16, pre-transposed)
        int n = i >> 4, kg = i & 15;
        *(half8*)(Ws + n * PITCH + kg * 8) = *(const half8*)(Wt + n * 128 + kg * 8);
    }
    __syncthreads();

    int wave = t >> 6, lane = t & 63;
    int m = lane & 15, quad = lane >> 4;
    int wrow = wave * 16;
    constexpr int NCT = FOUT / 16;
    floatx4 acc[NCT];
#pragma unroll
    for (int c = 0; c < NCT; ++c) acc[c] = (floatx4){0.f, 0.f, 0.f, 0.f};

#pragma unroll
    for (int kc = 0; kc < 4; ++kc) {
        half8 a = *(const half8*)(Xs + (wrow + m) * PITCH + kc * 32 + quad * 8);
#pragma unroll
        for (int c = 0; c < NCT; ++c) {
            half8 b = *(const half8*)(Ws + (c * 16 + m) * PITCH + kc * 32 + quad * 8);
            acc[c] = __builtin_amdgcn_mfma_f32_16x16x32_f16(a, b, acc[c], 0, 0, 0);
        }
    }

    // epilogue: row = row0 + wrow + quad*4 + r ; col = c*16 + m ; scale by dinv
    float dv[4];
    int rowb = row0 + wrow + quad * 4;
#pragma unroll
    for (int r = 0; r < 4; ++r) dv[r] = (rowb + r < NN) ? dinv[rowb + r] : 0.f;
#pragma unroll
    for (int c = 0; c < NCT; ++c) {
#pragma unroll
        for (int r = 0; r < 4; ++r) {
            int row = rowb + r;
            if (row < NN)
                Out[(size_t)row * FOUT + c * 16 + m] = __float2half(acc[c][r] * dv[r]);
        }
    }
}

// ---------- aggregation, 128 fp16 features -> fp16 out (relu) ----------
__global__ __launch_bounds__(256) void k_agg_relu128(
    const __half* __restrict__ G, const int* __restrict__ csr,
    const int* __restrict__ offs, const float* __restrict__ dinv,
    const float* __restrict__ bias, __half* __restrict__ Out) {
    int node = (blockIdx.x * 256 + threadIdx.x) >> 6;
    int lane = threadIdx.x & 63;
    if (node >= NN) return;
    const __half2* g = (const __half2*)G;  // 64 half2 per row
    float2 a0 = __half22float2(g[(size_t)node * 64 + lane]);  // self loop term
    float2 a1 = make_float2(0.f, 0.f);
    float2 a2 = make_float2(0.f, 0.f);
    float2 a3 = make_float2(0.f, 0.f);
    int e0 = offs[node], e1 = offs[node + 1];
    int e = e0;
    for (; e + 3 < e1; e += 4) {  // 4 independent gather chains (MLP)
        int s0 = csr[e], s1 = csr[e + 1], s2 = csr[e + 2], s3 = csr[e + 3];
        float2 v0 = __half22float2(g[(size_t)s0 * 64 + lane]);
        float2 v1 = __half22float2(g[(size_t)s1 * 64 + lane]);
        float2 v2 = __half22float2(g[(size_t)s2 * 64 + lane]);
        float2 v3 = __half22float2(g[(size_t)s3 * 64 + lane]);
        a0.x += v0.x; a0.y += v0.y;
        a1.x += v1.x; a1.y += v1.y;
        a2.x += v2.x; a2.y += v2.y;
        a3.x += v3.x; a3.y += v3.y;
    }
    for (; e < e1; ++e) {
        float2 v = __half22float2(g[(size_t)csr[e] * 64 + lane]);
        a0.x += v.x; a0.y += v.y;
    }
    float accx = (a0.x + a1.x) + (a2.x + a3.x);
    float accy = (a0.y + a1.y) + (a2.y + a3.y);
    float di = dinv[node];
    float2 b = ((const float2*)bias)[lane];
    float ox = fmaxf(accx * di + b.x, 0.f);
    float oy = fmaxf(accy * di + b.y, 0.f);
    ((__half2*)Out)[(size_t)node * 64 + lane] = __floats2half2_rn(ox, oy);
}

// ---------- aggregation, 64 fp16 features -> fp32 out ----------
__global__ __launch_bounds__(256) void k_agg64(
    const __half* __restrict__ G, const int* __restrict__ csr,
    const int* __restrict__ offs, const float* __restrict__ dinv,
    const float* __restrict__ bias, float* __restrict__ Out) {
    int node = (blockIdx.x * 256 + threadIdx.x) >> 6;
    int lane = threadIdx.x & 63;
    if (node >= NN) return;
    float a0 = __half2float(G[(size_t)node * 64 + lane]);  // self loop
    float a1 = 0.f, a2 = 0.f, a3 = 0.f;
    int e0 = offs[node], e1 = offs[node + 1];
    int e = e0;
    for (; e + 3 < e1; e += 4) {
        int s0 = csr[e], s1 = csr[e + 1], s2 = csr[e + 2], s3 = csr[e + 3];
        float v0 = __half2float(G[(size_t)s0 * 64 + lane]);
        float v1 = __half2float(G[(size_t)s1 * 64 + lane]);
        float v2 = __half2float(G[(size_t)s2 * 64 + lane]);
        float v3 = __half2float(G[(size_t)s3 * 64 + lane]);
        a0 += v0; a1 += v1; a2 += v2; a3 += v3;
    }
    for (; e < e1; ++e) a0 += __half2float(G[(size_t)csr[e] * 64 + lane]);
    float acc = (a0 + a1) + (a2 + a3);
    Out[(size_t)node * 64 + lane] = acc * dinv[node] + bias[lane];
}

// ---------- mean pool: one 64-thread block per graph, batch is sorted ----------
__global__ __launch_bounds__(64) void k_pool(const float* __restrict__ H,
                                             const int* __restrict__ batch,
                                             float* __restrict__ out) {
    int gph = blockIdx.x;
    int lo = 0, hi = NN;
    while (lo < hi) { int m = (lo + hi) >> 1; if (batch[m] < gph) lo = m + 1; else hi = m; }
    int s0 = lo;
    hi = NN;
    while (lo < hi) { int m = (lo + hi) >> 1; if (batch[m] <= gph) lo = m + 1; else hi = m; }
    int s1 = lo;
    int f = threadIdx.x;
    float s = 0.f;
    for (int n = s0; n < s1; ++n) s += H[(size_t)n * 64 + f];
    int cnt = s1 - s0;
    out[gph * 64 + f] = (cnt > 0) ? s / (float)cnt : 0.f;
}

extern "C" void kernel_launch(void* const* d_in, const int* in_sizes, int n_in,
                              void* d_out, int out_size, void* d_ws, size_t ws_size,
                              hipStream_t stream) {
    const float* x     = (const float*)d_in[0];
    const int*   ei    = (const int*)d_in[1];   // [2, NE] int32
    const int*   batch = (const int*)d_in[2];
    const float* W1    = (const float*)d_in[3];
    const float* b1    = (const float*)d_in[4];
    const float* W2    = (const float*)d_in[5];
    const float* b2    = (const float*)d_in[6];
    const int* esrc = ei;
    const int* edst = ei + NE;

    char* ws = (char*)d_ws;
    size_t off = 0;
    __half* G1  = (__half*)(ws + off); off += (size_t)NN * 128 * 2;  // fp16 g1
    __half* G2  = (__half*)(ws + off); off += (size_t)NN * 64 * 2;   // fp16 g2
    __half* B   = (__half*)(ws + off); off += (size_t)NN * 128 * 2;  // fp16 relu(agg1)
    float* AGG2 = (float*)(ws + off);  off += (size_t)NN * 64 * 4;   // fp32
    int*   csr  = (int*)(ws + off);    off += (size_t)NE * 4;
    int*   offs = (int*)(ws + off);    off += ((size_t)NN + 8) * 4;
    int*   cur  = (int*)(ws + off);    off += (size_t)NN * 4;
    int*   deg  = (int*)(ws + off);    off += (size_t)NN * 4;
    float* dinv = (float*)(ws + off);  off += (size_t)NN * 4;
    int*   bsum = (int*)(ws + off);    off += 512 * 4;
    int*   bbase= (int*)(ws + off);    off += 512 * 4;
    __half* Wt1 = (__half*)(ws + off); off += 128 * 128 * 2;
    __half* Wt2 = (__half*)(ws + off); off += 128 * 64 * 2;

    hipMemsetAsync(deg, 0, NN * sizeof(int), stream);
    k_hist<<<2048, 256, 0, stream>>>(edst, deg);
    k_dinv<<<(NN + 255) / 256, 256, 0, stream>>>(deg, dinv);

    // 3-phase parallel exclusive scan
    k_bsum<<<NBLK, 256, 0, stream>>>(deg, bsum);
    k_bscan<<<1, 512, 0, stream>>>(bsum, bbase);
    k_chunkscan<<<NBLK, 256, 0, stream>>>(deg, bbase, offs, cur);

    k_scatter<<<2048, 256, 0, stream>>>(esrc, edst, cur, csr);

    // weight transpose+cast (tiny)
    k_wt<<<64, 256, 0, stream>>>(W1, Wt1, 128);
    k_wt<<<32, 256, 0, stream>>>(W2, Wt2, 64);

    const int MMB = (NN + 63) / 64;  // 1563
    // layer 1: G1 = fp16(dinv ⊙ (x @ W1));  B = fp16(relu(dinv ⊙ csr_sum(G1) + b1))
    k_mm_mfma<128, false><<<MMB, 256, 0, stream>>>(x, Wt1, dinv, G1);
    k_agg_relu128<<<(NN + 3) / 4, 256, 0, stream>>>(G1, csr, offs, dinv, b1, B);

    // layer 2: G2 = fp16(dinv ⊙ (B @ W2));  AGG2 = dinv ⊙ csr_sum(G2) + b2
    k_mm_mfma<64, true><<<MMB, 256, 0, stream>>>(B, Wt2, dinv, G2);
    k_agg64<<<(NN + 3) / 4, 256, 0, stream>>>(G2, csr, offs, dinv, b2, AGG2);

    // pool
    k_pool<<<NG, 64, 0, stream>>>(AGG2, batch, (float*)d_out);
}

// Round 5
// 479.861 us; speedup vs baseline: 2.1507x; 1.1613x over previous
//
#include <hip/hip_runtime.h>
#include <hip/hip_fp16.h>

#define NN 100000   // nodes
#define NE 1600000  // edges
#define NG 512      // graphs
#define NBLK 391    // ceil(NN/256) = scan blocks = coarse buckets (dst>>8)
#define EPB 8192    // edges per k_csort batch
#define NCB 196     // ceil(NE/EPB)
// IN=128, HID=128, OUT=64

typedef _Float16 half8 __attribute__((ext_vector_type(8)));
typedef _Float16 half4v __attribute__((ext_vector_type(4)));
typedef float floatx4 __attribute__((ext_vector_type(4)));

// ---------- degree histogram ----------
__global__ void k_hist(const int* __restrict__ dst, int* __restrict__ deg) {
    int i = blockIdx.x * blockDim.x + threadIdx.x;
    int stride = gridDim.x * blockDim.x;
    for (; i < NE; i += stride) atomicAdd(&deg[dst[i]], 1);
}

// ---------- dinv = rsqrt(in_deg + 1)  (self loop) ----------
__global__ void k_dinv(const int* __restrict__ deg, float* __restrict__ dinv) {
    int i = blockIdx.x * blockDim.x + threadIdx.x;
    if (i < NN) dinv[i] = rsqrtf((float)(deg[i] + 1));
}

// ---------- 3-phase exclusive scan of deg -> offs[NN+1]; bbase doubles as bucket bases ----------
__global__ __launch_bounds__(256) void k_bsum(const int* __restrict__ deg,
                                              int* __restrict__ bsum) {
    __shared__ int red[256];
    int t = threadIdx.x;
    int i = blockIdx.x * 256 + t;
    red[t] = (i < NN) ? deg[i] : 0;
    __syncthreads();
    for (int d = 128; d > 0; d >>= 1) {
        if (t < d) red[t] += red[t + d];
        __syncthreads();
    }
    if (t == 0) bsum[blockIdx.x] = red[0];
}

__global__ __launch_bounds__(512) void k_bscan(const int* __restrict__ bsum,
                                               int* __restrict__ bbase,
                                               int* __restrict__ gcur) {
    __shared__ int s[512];
    int t = threadIdx.x;
    int v = (t < NBLK) ? bsum[t] : 0;
    s[t] = v;
    __syncthreads();
    for (int d = 1; d < 512; d <<= 1) {
        int u = (t >= d) ? s[t - d] : 0;
        __syncthreads();
        s[t] += u;
        __syncthreads();
    }
    if (t < NBLK) {
        int ex = s[t] - v;       // exclusive base per bucket
        bbase[t] = ex;
        gcur[t] = ex;            // running cursor for k_csort
    }
    if (t == 0) bbase[NBLK] = NE;
}

__global__ __launch_bounds__(256) void k_chunkscan(const int* __restrict__ deg,
                                                   const int* __restrict__ bbase,
                                                   int* __restrict__ offs) {
    __shared__ int s[256];
    int t = threadIdx.x;
    int i = blockIdx.x * 256 + t;
    int v = (i < NN) ? deg[i] : 0;
    s[t] = v;
    __syncthreads();
    for (int d = 1; d < 256; d <<= 1) {
        int u = (t >= d) ? s[t - d] : 0;
        __syncthreads();
        s[t] += u;
        __syncthreads();
    }
    if (i < NN) offs[i] = bbase[blockIdx.x] + s[t] - v;
    if (i == 0) offs[NN] = NE;
}

// ---------- phase C: batch counting-sort edges into coarse-bucket regions ----------
// Each block sorts one EPB-edge batch by bucket (dst>>8) in LDS, then flushes
// bucket-contiguous runs with coalesced stores. Entry = (dst&255)<<24 | src.
__global__ __launch_bounds__(256) void k_csort(const int* __restrict__ src,
                                               const int* __restrict__ dst,
                                               int* __restrict__ gcur,
                                               unsigned* __restrict__ pairbuf) {
    __shared__ int hcnt[NBLK];
    __shared__ int lbase[NBLK];
    __shared__ int lcur[NBLK];
    __shared__ int gbase[NBLK];
    __shared__ int ss[512];
    __shared__ unsigned sorted[EPB];
    __shared__ unsigned short bkt[EPB];
    int t = threadIdx.x;
    int e0 = blockIdx.x * EPB;
    int e1 = e0 + EPB; if (e1 > NE) e1 = NE;
    int n = e1 - e0;

    for (int i = t; i < NBLK; i += 256) hcnt[i] = 0;
    __syncthreads();
    // pass 1: bucket histogram
    for (int i = e0 + t; i < e1; i += 256)
        atomicAdd(&hcnt[dst[i] >> 8], 1);
    __syncthreads();
    // exclusive scan of hcnt[391] (padded to 512, 2 slots/thread Hillis-Steele)
    ss[t]       = (t < NBLK) ? hcnt[t] : 0;
    ss[t + 256] = (t + 256 < NBLK) ? hcnt[t + 256] : 0;
    __syncthreads();
    for (int d = 1; d < 512; d <<= 1) {
        int v1 = (t >= d) ? ss[t - d] : 0;
        int v2 = ss[t + 256 - d];
        __syncthreads();
        ss[t] += v1; ss[t + 256] += v2;
        __syncthreads();
    }
    for (int i = t; i < NBLK; i += 256) {
        int ex = ss[i] - hcnt[i];
        lbase[i] = ex;
        lcur[i] = ex;
        if (hcnt[i] > 0) gbase[i] = atomicAdd(&gcur[i], hcnt[i]);
    }
    __syncthreads();
    // pass 2: place into LDS, bucket-grouped
    for (int i = e0 + t; i < e1; i += 256) {
        int d = dst[i];
        int b = d >> 8;
        int pos = atomicAdd(&lcur[b], 1);
        sorted[pos] = ((unsigned)(d & 255) << 24) | (unsigned)src[i];
        bkt[pos] = (unsigned short)b;
    }
    __syncthreads();
    // pass 3: coalesced flush (consecutive i -> mostly same bucket -> consecutive addr)
    for (int i = t; i < n; i += 256) {
        int b = bkt[i];
        pairbuf[gbase[b] + (i - lbase[b])] = sorted[i];
    }
}

// ---------- phase D: within-bucket placement into final CSR ----------
// Block b owns nodes [b*256, b*256+256); all stores land in its contiguous csr window.
__global__ __launch_bounds__(256) void k_place(const unsigned* __restrict__ pairbuf,
                                               const int* __restrict__ bbase,
                                               const int* __restrict__ offs,
                                               int* __restrict__ csr) {
    __shared__ int lcur[256];
    int t = threadIdx.x;
    int b = blockIdx.x;
    int base = bbase[b];
    int cnt = bbase[b + 1] - base;
    int node0 = b << 8;
    lcur[t] = 0;
    __syncthreads();
    for (int i = t; i < cnt; i += 256) {
        unsigned e = pairbuf[base + i];
        int dlow = e >> 24;
        int src = (int)(e & 0xFFFFFFu);
        int slot = atomicAdd(&lcur[dlow], 1);
        csr[offs[node0 + dlow] + slot] = src;
    }
}

// ---------- W [128][FOUT] fp32 -> Wt [FOUT][128] fp16 (transpose+cast) ----------
__global__ void k_wt(const float* __restrict__ W, __half* __restrict__ Wt, int fout) {
    int idx = blockIdx.x * 256 + threadIdx.x;
    if (idx < 128 * fout) {
        int k = idx / fout, n = idx % fout;
        Wt[n * 128 + k] = __float2half(W[idx]);
    }
}

// ---------- MFMA matmul: Out = fp16( dinv ⊙ (X @ W) ), K=128 ----------
template <int FOUT, bool HALF_IN>
__global__ __launch_bounds__(256) void k_mm_mfma(const void* __restrict__ Xv,
                                                 const __half* __restrict__ Wt,
                                                 const float* __restrict__ dinv,
                                                 __half* __restrict__ Out) {
    constexpr int PITCH = 136;
    __shared__ _Float16 Xs[64 * PITCH];
    __shared__ _Float16 Ws[FOUT * PITCH];
    int t = threadIdx.x;
    int row0 = blockIdx.x * 64;

    if (HALF_IN) {
        const __half* X = (const __half*)Xv;
        for (int i = t; i < 64 * 16; i += 256) {
            int r = i >> 4, kg = i & 15;
            int row = row0 + r;
            half8 v = {};
            if (row < NN) v = *(const half8*)(X + (size_t)row * 128 + kg * 8);
            *(half8*)(Xs + r * PITCH + kg * 8) = v;
        }
    } else {
        const float* X = (const float*)Xv;
        for (int i = t; i < 64 * 32; i += 256) {
            int r = i >> 5, f4 = i & 31;
            int row = row0 + r;
            half4v h = {};
            if (row < NN) {
                float4 v = *(const float4*)(X + (size_t)row * 128 + f4 * 4);
                h[0] = (_Float16)v.x; h[1] = (_Float16)v.y;
                h[2] = (_Float16)v.z; h[3] = (_Float16)v.w;
            }
            *(half4v*)(Xs + r * PITCH + f4 * 4) = h;
        }
    }
    for (int i = t; i < FOUT * 16; i += 256) {
        int n = i >> 4, kg = i & 15;
        *(half8*)(Ws + n * PITCH + kg * 8) = *(const half8*)(Wt + n * 128 + kg * 8);
    }
    __syncthreads();

    int wave = t >> 6, lane = t & 63;
    int m = lane & 15, quad = lane >> 4;
    int wrow = wave * 16;
    constexpr int NCT = FOUT / 16;
    floatx4 acc[NCT];
#pragma unroll
    for (int c = 0; c < NCT; ++c) acc[c] = (floatx4){0.f, 0.f, 0.f, 0.f};

#pragma unroll
    for (int kc = 0; kc < 4; ++kc) {
        half8 a = *(const half8*)(Xs + (wrow + m) * PITCH + kc * 32 + quad * 8);
#pragma unroll
        for (int c = 0; c < NCT; ++c) {
            half8 b = *(const half8*)(Ws + (c * 16 + m) * PITCH + kc * 32 + quad * 8);
            acc[c] = __builtin_amdgcn_mfma_f32_16x16x32_f16(a, b, acc[c], 0, 0, 0);
        }
    }

    float dv[4];
    int rowb = row0 + wrow + quad * 4;
#pragma unroll
    for (int r = 0; r < 4; ++r) dv[r] = (rowb + r < NN) ? dinv[rowb + r] : 0.f;
#pragma unroll
    for (int c = 0; c < NCT; ++c) {
#pragma unroll
        for (int r = 0; r < 4; ++r) {
            int row = rowb + r;
            if (row < NN)
                Out[(size_t)row * FOUT + c * 16 + m] = __float2half(acc[c][r] * dv[r]);
        }
    }
}

// ---------- aggregation, 128 fp16 features -> fp16 out (relu) ----------
__global__ __launch_bounds__(256) void k_agg_relu128(
    const __half* __restrict__ G, const int* __restrict__ csr,
    const int* __restrict__ offs, const float* __restrict__ dinv,
    const float* __restrict__ bias, __half* __restrict__ Out) {
    int node = (blockIdx.x * 256 + threadIdx.x) >> 6;
    int lane = threadIdx.x & 63;
    if (node >= NN) return;
    const __half2* g = (const __half2*)G;
    float2 a0 = __half22float2(g[(size_t)node * 64 + lane]);
    float2 a1 = make_float2(0.f, 0.f);
    float2 a2 = make_float2(0.f, 0.f);
    float2 a3 = make_float2(0.f, 0.f);
    int e0 = offs[node], e1 = offs[node + 1];
    int e = e0;
    for (; e + 3 < e1; e += 4) {
        int s0 = csr[e], s1 = csr[e + 1], s2 = csr[e + 2], s3 = csr[e + 3];
        float2 v0 = __half22float2(g[(size_t)s0 * 64 + lane]);
        float2 v1 = __half22float2(g[(size_t)s1 * 64 + lane]);
        float2 v2 = __half22float2(g[(size_t)s2 * 64 + lane]);
        float2 v3 = __half22float2(g[(size_t)s3 * 64 + lane]);
        a0.x += v0.x; a0.y += v0.y;
        a1.x += v1.x; a1.y += v1.y;
        a2.x += v2.x; a2.y += v2.y;
        a3.x += v3.x; a3.y += v3.y;
    }
    for (; e < e1; ++e) {
        float2 v = __half22float2(g[(size_t)csr[e] * 64 + lane]);
        a0.x += v.x; a0.y += v.y;
    }
    float accx = (a0.x + a1.x) + (a2.x + a3.x);
    float accy = (a0.y + a1.y) + (a2.y + a3.y);
    float di = dinv[node];
    float2 b = ((const float2*)bias)[lane];
    float ox = fmaxf(accx * di + b.x, 0.f);
    float oy = fmaxf(accy * di + b.y, 0.f);
    ((__half2*)Out)[(size_t)node * 64 + lane] = __floats2half2_rn(ox, oy);
}

// ---------- aggregation, 64 fp16 features -> fp32 out ----------
__global__ __launch_bounds__(256) void k_agg64(
    const __half* __restrict__ G, const int* __restrict__ csr,
    const int* __restrict__ offs, const float* __restrict__ dinv,
    const float* __restrict__ bias, float* __restrict__ Out) {
    int node = (blockIdx.x * 256 + threadIdx.x) >> 6;
    int lane = threadIdx.x & 63;
    if (node >= NN) return;
    float a0 = __half2float(G[(size_t)node * 64 + lane]);
    float a1 = 0.f, a2 = 0.f, a3 = 0.f;
    int e0 = offs[node], e1 = offs[node + 1];
    int e = e0;
    for (; e + 3 < e1; e += 4) {
        int s0 = csr[e], s1 = csr[e + 1], s2 = csr[e + 2], s3 = csr[e + 3];
        float v0 = __half2float(G[(size_t)s0 * 64 + lane]);
        float v1 = __half2float(G[(size_t)s1 * 64 + lane]);
        float v2 = __half2float(G[(size_t)s2 * 64 + lane]);
        float v3 = __half2float(G[(size_t)s3 * 64 + lane]);
        a0 += v0; a1 += v1; a2 += v2; a3 += v3;
    }
    for (; e < e1; ++e) a0 += __half2float(G[(size_t)csr[e] * 64 + lane]);
    float acc = (a0 + a1) + (a2 + a3);
    Out[(size_t)node * 64 + lane] = acc * dinv[node] + bias[lane];
}

// ---------- mean pool ----------
__global__ __launch_bounds__(64) void k_pool(const float* __restrict__ H,
                                             const int* __restrict__ batch,
                                             float* __restrict__ out) {
    int gph = blockIdx.x;
    int lo = 0, hi = NN;
    while (lo < hi) { int m = (lo + hi) >> 1; if (batch[m] < gph) lo = m + 1; else hi = m; }
    int s0 = lo;
    hi = NN;
    while (lo < hi) { int m = (lo + hi) >> 1; if (batch[m] <= gph) lo = m + 1; else hi = m; }
    int s1 = lo;
    int f = threadIdx.x;
    float s = 0.f;
    for (int n = s0; n < s1; ++n) s += H[(size_t)n * 64 + f];
    int cnt = s1 - s0;
    out[gph * 64 + f] = (cnt > 0) ? s / (float)cnt : 0.f;
}

extern "C" void kernel_launch(void* const* d_in, const int* in_sizes, int n_in,
                              void* d_out, int out_size, void* d_ws, size_t ws_size,
                              hipStream_t stream) {
    const float* x     = (const float*)d_in[0];
    const int*   ei    = (const int*)d_in[1];   // [2, NE] int32
    const int*   batch = (const int*)d_in[2];
    const float* W1    = (const float*)d_in[3];
    const float* b1    = (const float*)d_in[4];
    const float* W2    = (const float*)d_in[5];
    const float* b2    = (const float*)d_in[6];
    const int* esrc = ei;
    const int* edst = ei + NE;

    char* ws = (char*)d_ws;
    size_t off = 0;
    __half* G1  = (__half*)(ws + off); off += (size_t)NN * 128 * 2;
    __half* G2  = (__half*)(ws + off); off += (size_t)NN * 64 * 2;
    __half* B   = (__half*)(ws + off); off += (size_t)NN * 128 * 2;
    float* AGG2 = (float*)(ws + off);  off += (size_t)NN * 64 * 4;
    int*   csr  = (int*)(ws + off);    off += (size_t)NE * 4;
    unsigned* pairbuf = (unsigned*)(ws + off); off += (size_t)NE * 4;
    int*   offs = (int*)(ws + off);    off += ((size_t)NN + 8) * 4;
    int*   deg  = (int*)(ws + off);    off += (size_t)NN * 4;
    float* dinv = (float*)(ws + off);  off += (size_t)NN * 4;
    int*   bsum = (int*)(ws + off);    off += 512 * 4;
    int*   bbase= (int*)(ws + off);    off += 512 * 4;
    int*   gcur = (int*)(ws + off);    off += 512 * 4;
    __half* Wt1 = (__half*)(ws + off); off += 128 * 128 * 2;
    __half* Wt2 = (__half*)(ws + off); off += 128 * 64 * 2;

    hipMemsetAsync(deg, 0, NN * sizeof(int), stream);
    k_hist<<<2048, 256, 0, stream>>>(edst, deg);
    k_dinv<<<(NN + 255) / 256, 256, 0, stream>>>(deg, dinv);

    // scan: per-bucket sums/bases (reused by csort) + per-node offsets
    k_bsum<<<NBLK, 256, 0, stream>>>(deg, bsum);
    k_bscan<<<1, 512, 0, stream>>>(bsum, bbase, gcur);
    k_chunkscan<<<NBLK, 256, 0, stream>>>(deg, bbase, offs);

    // two-phase CSR build (replaces 133 µs random scatter)
    k_csort<<<NCB, 256, 0, stream>>>(esrc, edst, gcur, pairbuf);
    k_place<<<NBLK, 256, 0, stream>>>(pairbuf, bbase, offs, csr);

    // weight transpose+cast (tiny)
    k_wt<<<64, 256, 0, stream>>>(W1, Wt1, 128);
    k_wt<<<32, 256, 0, stream>>>(W2, Wt2, 64);

    const int MMB = (NN + 63) / 64;
    k_mm_mfma<128, false><<<MMB, 256, 0, stream>>>(x, Wt1, dinv, G1);
    k_agg_relu128<<<(NN + 3) / 4, 256, 0, stream>>>(G1, csr, offs, dinv, b1, B);
    k_mm_mfma<64, true><<<MMB, 256, 0, stream>>>(B, Wt2, dinv, G2);
    k_agg64<<<(NN + 3) / 4, 256, 0, stream>>>(G2, csr, offs, dinv, b2, AGG2);

    k_pool<<<NG, 64, 0, stream>>>(AGG2, batch, (float*)d_out);
}

// Round 6
// 424.275 us; speedup vs baseline: 2.4325x; 1.1310x over previous
//
#include <hip/hip_runtime.h>
#include <hip/hip_fp16.h>

#define NN 100000   // nodes
#define NE 1600000  // edges
#define NG 512      // graphs
#define NBLK 391    // ceil(NN/256) = scan blocks = coarse buckets (dst>>8)
#define EPB 8192    // edges per k_csort batch
#define NCB 196     // ceil(NE/EPB)
// IN=128, HID=128, OUT=64

typedef _Float16 half8 __attribute__((ext_vector_type(8)));
typedef _Float16 half4v __attribute__((ext_vector_type(4)));
typedef float floatx4 __attribute__((ext_vector_type(4)));

// ---------- degree histogram ----------
__global__ void k_hist(const int* __restrict__ dst, int* __restrict__ deg) {
    int i = blockIdx.x * blockDim.x + threadIdx.x;
    int stride = gridDim.x * blockDim.x;
    for (; i < NE; i += stride) atomicAdd(&deg[dst[i]], 1);
}

// ---------- dinv = rsqrt(in_deg + 1)  (self loop) ----------
__global__ void k_dinv(const int* __restrict__ deg, float* __restrict__ dinv) {
    int i = blockIdx.x * blockDim.x + threadIdx.x;
    if (i < NN) dinv[i] = rsqrtf((float)(deg[i] + 1));
}

// ---------- 3-phase exclusive scan of deg -> offs[NN+1]; bbase doubles as bucket bases ----------
__global__ __launch_bounds__(256) void k_bsum(const int* __restrict__ deg,
                                              int* __restrict__ bsum) {
    __shared__ int red[256];
    int t = threadIdx.x;
    int i = blockIdx.x * 256 + t;
    red[t] = (i < NN) ? deg[i] : 0;
    __syncthreads();
    for (int d = 128; d > 0; d >>= 1) {
        if (t < d) red[t] += red[t + d];
        __syncthreads();
    }
    if (t == 0) bsum[blockIdx.x] = red[0];
}

__global__ __launch_bounds__(512) void k_bscan(const int* __restrict__ bsum,
                                               int* __restrict__ bbase,
                                               int* __restrict__ gcur) {
    __shared__ int s[512];
    int t = threadIdx.x;
    int v = (t < NBLK) ? bsum[t] : 0;
    s[t] = v;
    __syncthreads();
    for (int d = 1; d < 512; d <<= 1) {
        int u = (t >= d) ? s[t - d] : 0;
        __syncthreads();
        s[t] += u;
        __syncthreads();
    }
    if (t < NBLK) {
        int ex = s[t] - v;       // exclusive base per bucket
        bbase[t] = ex;
        gcur[t] = ex;            // running cursor for k_csort
    }
    if (t == 0) bbase[NBLK] = NE;
}

__global__ __launch_bounds__(256) void k_chunkscan(const int* __restrict__ deg,
                                                   const int* __restrict__ bbase,
                                                   int* __restrict__ offs) {
    __shared__ int s[256];
    int t = threadIdx.x;
    int i = blockIdx.x * 256 + t;
    int v = (i < NN) ? deg[i] : 0;
    s[t] = v;
    __syncthreads();
    for (int d = 1; d < 256; d <<= 1) {
        int u = (t >= d) ? s[t - d] : 0;
        __syncthreads();
        s[t] += u;
        __syncthreads();
    }
    if (i < NN) offs[i] = bbase[blockIdx.x] + s[t] - v;
    if (i == 0) offs[NN] = NE;
}

// ---------- phase C: batch counting-sort edges into coarse-bucket regions ----------
__global__ __launch_bounds__(256) void k_csort(const int* __restrict__ src,
                                               const int* __restrict__ dst,
                                               int* __restrict__ gcur,
                                               unsigned* __restrict__ pairbuf) {
    __shared__ int hcnt[NBLK];
    __shared__ int lbase[NBLK];
    __shared__ int lcur[NBLK];
    __shared__ int gbase[NBLK];
    __shared__ int ss[512];
    __shared__ unsigned sorted[EPB];
    __shared__ unsigned short bkt[EPB];
    int t = threadIdx.x;
    int e0 = blockIdx.x * EPB;
    int e1 = e0 + EPB; if (e1 > NE) e1 = NE;
    int n = e1 - e0;

    for (int i = t; i < NBLK; i += 256) hcnt[i] = 0;
    __syncthreads();
    for (int i = e0 + t; i < e1; i += 256)
        atomicAdd(&hcnt[dst[i] >> 8], 1);
    __syncthreads();
    ss[t]       = (t < NBLK) ? hcnt[t] : 0;
    ss[t + 256] = (t + 256 < NBLK) ? hcnt[t + 256] : 0;
    __syncthreads();
    for (int d = 1; d < 512; d <<= 1) {
        int v1 = (t >= d) ? ss[t - d] : 0;
        int v2 = ss[t + 256 - d];
        __syncthreads();
        ss[t] += v1; ss[t + 256] += v2;
        __syncthreads();
    }
    for (int i = t; i < NBLK; i += 256) {
        int ex = ss[i] - hcnt[i];
        lbase[i] = ex;
        lcur[i] = ex;
        if (hcnt[i] > 0) gbase[i] = atomicAdd(&gcur[i], hcnt[i]);
    }
    __syncthreads();
    for (int i = e0 + t; i < e1; i += 256) {
        int d = dst[i];
        int b = d >> 8;
        int pos = atomicAdd(&lcur[b], 1);
        sorted[pos] = ((unsigned)(d & 255) << 24) | (unsigned)src[i];
        bkt[pos] = (unsigned short)b;
    }
    __syncthreads();
    for (int i = t; i < n; i += 256) {
        int b = bkt[i];
        pairbuf[gbase[b] + (i - lbase[b])] = sorted[i];
    }
}

// ---------- phase D: within-bucket placement into final CSR ----------
__global__ __launch_bounds__(256) void k_place(const unsigned* __restrict__ pairbuf,
                                               const int* __restrict__ bbase,
                                               const int* __restrict__ offs,
                                               int* __restrict__ csr) {
    __shared__ int lcur[256];
    int t = threadIdx.x;
    int b = blockIdx.x;
    int base = bbase[b];
    int cnt = bbase[b + 1] - base;
    int node0 = b << 8;
    lcur[t] = 0;
    __syncthreads();
    for (int i = t; i < cnt; i += 256) {
        unsigned e = pairbuf[base + i];
        int dlow = e >> 24;
        int src = (int)(e & 0xFFFFFFu);
        int slot = atomicAdd(&lcur[dlow], 1);
        csr[offs[node0 + dlow] + slot] = src;
    }
}

// ---------- W [128][FOUT] fp32 -> Wt [FOUT][128] fp16 (transpose+cast) ----------
__global__ void k_wt(const float* __restrict__ W, __half* __restrict__ Wt, int fout) {
    int idx = blockIdx.x * 256 + threadIdx.x;
    if (idx < 128 * fout) {
        int k = idx / fout, n = idx % fout;
        Wt[n * 128 + k] = __float2half(W[idx]);
    }
}

// ---------- MFMA matmul: Out = fp16( dinv ⊙ (X @ W) ), K=128 ----------
template <int FOUT, bool HALF_IN>
__global__ __launch_bounds__(256) void k_mm_mfma(const void* __restrict__ Xv,
                                                 const __half* __restrict__ Wt,
                                                 const float* __restrict__ dinv,
                                                 __half* __restrict__ Out) {
    constexpr int PITCH = 136;
    __shared__ _Float16 Xs[64 * PITCH];
    __shared__ _Float16 Ws[FOUT * PITCH];
    int t = threadIdx.x;
    int row0 = blockIdx.x * 64;

    if (HALF_IN) {
        const __half* X = (const __half*)Xv;
        for (int i = t; i < 64 * 16; i += 256) {
            int r = i >> 4, kg = i & 15;
            int row = row0 + r;
            half8 v = {};
            if (row < NN) v = *(const half8*)(X + (size_t)row * 128 + kg * 8);
            *(half8*)(Xs + r * PITCH + kg * 8) = v;
        }
    } else {
        const float* X = (const float*)Xv;
        for (int i = t; i < 64 * 32; i += 256) {
            int r = i >> 5, f4 = i & 31;
            int row = row0 + r;
            half4v h = {};
            if (row < NN) {
                float4 v = *(const float4*)(X + (size_t)row * 128 + f4 * 4);
                h[0] = (_Float16)v.x; h[1] = (_Float16)v.y;
                h[2] = (_Float16)v.z; h[3] = (_Float16)v.w;
            }
            *(half4v*)(Xs + r * PITCH + f4 * 4) = h;
        }
    }
    for (int i = t; i < FOUT * 16; i += 256) {
        int n = i >> 4, kg = i & 15;
        *(half8*)(Ws + n * PITCH + kg * 8) = *(const half8*)(Wt + n * 128 + kg * 8);
    }
    __syncthreads();

    int wave = t >> 6, lane = t & 63;
    int m = lane & 15, quad = lane >> 4;
    int wrow = wave * 16;
    constexpr int NCT = FOUT / 16;
    floatx4 acc[NCT];
#pragma unroll
    for (int c = 0; c < NCT; ++c) acc[c] = (floatx4){0.f, 0.f, 0.f, 0.f};

#pragma unroll
    for (int kc = 0; kc < 4; ++kc) {
        half8 a = *(const half8*)(Xs + (wrow + m) * PITCH + kc * 32 + quad * 8);
#pragma unroll
        for (int c = 0; c < NCT; ++c) {
            half8 b = *(const half8*)(Ws + (c * 16 + m) * PITCH + kc * 32 + quad * 8);
            acc[c] = __builtin_amdgcn_mfma_f32_16x16x32_f16(a, b, acc[c], 0, 0, 0);
        }
    }

    float dv[4];
    int rowb = row0 + wrow + quad * 4;
#pragma unroll
    for (int r = 0; r < 4; ++r) dv[r] = (rowb + r < NN) ? dinv[rowb + r] : 0.f;
#pragma unroll
    for (int c = 0; c < NCT; ++c) {
#pragma unroll
        for (int r = 0; r < 4; ++r) {
            int row = rowb + r;
            if (row < NN)
                Out[(size_t)row * FOUT + c * 16 + m] = __float2half(acc[c][r] * dv[r]);
        }
    }
}

// ---------- aggregation, 128 fp16 features -> fp16 out (relu) ----------
__global__ __launch_bounds__(256) void k_agg_relu128(
    const __half* __restrict__ G, const int* __restrict__ csr,
    const int* __restrict__ offs, const float* __restrict__ dinv,
    const float* __restrict__ bias, __half* __restrict__ Out) {
    int node = (blockIdx.x * 256 + threadIdx.x) >> 6;
    int lane = threadIdx.x & 63;
    if (node >= NN) return;
    const __half2* g = (const __half2*)G;
    float2 a0 = __half22float2(g[(size_t)node * 64 + lane]);
    float2 a1 = make_float2(0.f, 0.f);
    float2 a2 = make_float2(0.f, 0.f);
    float2 a3 = make_float2(0.f, 0.f);
    int e0 = offs[node], e1 = offs[node + 1];
    int e = e0;
    for (; e + 3 < e1; e += 4) {
        int s0 = csr[e], s1 = csr[e + 1], s2 = csr[e + 2], s3 = csr[e + 3];
        float2 v0 = __half22float2(g[(size_t)s0 * 64 + lane]);
        float2 v1 = __half22float2(g[(size_t)s1 * 64 + lane]);
        float2 v2 = __half22float2(g[(size_t)s2 * 64 + lane]);
        float2 v3 = __half22float2(g[(size_t)s3 * 64 + lane]);
        a0.x += v0.x; a0.y += v0.y;
        a1.x += v1.x; a1.y += v1.y;
        a2.x += v2.x; a2.y += v2.y;
        a3.x += v3.x; a3.y += v3.y;
    }
    for (; e < e1; ++e) {
        float2 v = __half22float2(g[(size_t)csr[e] * 64 + lane]);
        a0.x += v.x; a0.y += v.y;
    }
    float accx = (a0.x + a1.x) + (a2.x + a3.x);
    float accy = (a0.y + a1.y) + (a2.y + a3.y);
    float di = dinv[node];
    float2 b = ((const float2*)bias)[lane];
    float ox = fmaxf(accx * di + b.x, 0.f);
    float oy = fmaxf(accy * di + b.y, 0.f);
    ((__half2*)Out)[(size_t)node * 64 + lane] = __floats2half2_rn(ox, oy);
}

// ---------- aggregation, 64 fp16 features -> fp32 out ----------
__global__ __launch_bounds__(256) void k_agg64(
    const __half* __restrict__ G, const int* __restrict__ csr,
    const int* __restrict__ offs, const float* __restrict__ dinv,
    const float* __restrict__ bias, float* __restrict__ Out) {
    int node = (blockIdx.x * 256 + threadIdx.x) >> 6;
    int lane = threadIdx.x & 63;
    if (node >= NN) return;
    float a0 = __half2float(G[(size_t)node * 64 + lane]);
    float a1 = 0.f, a2 = 0.f, a3 = 0.f;
    int e0 = offs[node], e1 = offs[node + 1];
    int e = e0;
    for (; e + 3 < e1; e += 4) {
        int s0 = csr[e], s1 = csr[e + 1], s2 = csr[e + 2], s3 = csr[e + 3];
        float v0 = __half2float(G[(size_t)s0 * 64 + lane]);
        float v1 = __half2float(G[(size_t)s1 * 64 + lane]);
        float v2 = __half2float(G[(size_t)s2 * 64 + lane]);
        float v3 = __half2float(G[(size_t)s3 * 64 + lane]);
        a0 += v0; a1 += v1; a2 += v2; a3 += v3;
    }
    for (; e < e1; ++e) a0 += __half2float(G[(size_t)csr[e] * 64 + lane]);
    float acc = (a0 + a1) + (a2 + a3);
    Out[(size_t)node * 64 + lane] = acc * dinv[node] + bias[lane];
}

// ---------- mean pool: 1 block/graph, 256 thr = 64 features x 4 row-slices ----------
__global__ __launch_bounds__(256) void k_pool(const float* __restrict__ H,
                                              const int* __restrict__ batch,
                                              float* __restrict__ out) {
    __shared__ float red[256];
    int gph = blockIdx.x;
    int lo = 0, hi = NN;
    while (lo < hi) { int m = (lo + hi) >> 1; if (batch[m] < gph) lo = m + 1; else hi = m; }
    int s0 = lo;
    hi = NN;
    while (lo < hi) { int m = (lo + hi) >> 1; if (batch[m] <= gph) lo = m + 1; else hi = m; }
    int s1 = lo;
    int t = threadIdx.x;
    int f = t & 63, rw = t >> 6;
    float s = 0.f;
    for (int n = s0 + rw; n < s1; n += 4) s += H[(size_t)n * 64 + f];
    red[t] = s;
    __syncthreads();
    if (rw == 0) {
        float tot = (red[f] + red[64 + f]) + (red[128 + f] + red[192 + f]);
        int cnt = s1 - s0;
        out[gph * 64 + f] = (cnt > 0) ? tot / (float)cnt : 0.f;
    }
}

extern "C" void kernel_launch(void* const* d_in, const int* in_sizes, int n_in,
                              void* d_out, int out_size, void* d_ws, size_t ws_size,
                              hipStream_t stream) {
    const float* x     = (const float*)d_in[0];
    const int*   ei    = (const int*)d_in[1];   // [2, NE] int32
    const int*   batch = (const int*)d_in[2];
    const float* W1    = (const float*)d_in[3];
    const float* b1    = (const float*)d_in[4];
    const float* W2    = (const float*)d_in[5];
    const float* b2    = (const float*)d_in[6];
    const int* esrc = ei;
    const int* edst = ei + NE;

    char* ws = (char*)d_ws;
    size_t off = 0;
    __half* G1  = (__half*)(ws + off); off += (size_t)NN * 128 * 2;
    __half* G2  = (__half*)(ws + off); off += (size_t)NN * 64 * 2;
    __half* B   = (__half*)(ws + off); off += (size_t)NN * 128 * 2;
    float* AGG2 = (float*)(ws + off);  off += (size_t)NN * 64 * 4;
    int*   csr  = (int*)(ws + off);    off += (size_t)NE * 4;
    unsigned* pairbuf = (unsigned*)(ws + off); off += (size_t)NE * 4;
    int*   offs = (int*)(ws + off);    off += ((size_t)NN + 8) * 4;
    int*   deg  = (int*)(ws + off);    off += (size_t)NN * 4;
    float* dinv = (float*)(ws + off);  off += (size_t)NN * 4;
    int*   bsum = (int*)(ws + off);    off += 512 * 4;
    int*   bbase= (int*)(ws + off);    off += 512 * 4;
    int*   gcur = (int*)(ws + off);    off += 512 * 4;
    __half* Wt1 = (__half*)(ws + off); off += 128 * 128 * 2;
    __half* Wt2 = (__half*)(ws + off); off += 128 * 64 * 2;

    hipMemsetAsync(deg, 0, NN * sizeof(int), stream);
    k_hist<<<2048, 256, 0, stream>>>(edst, deg);
    k_dinv<<<(NN + 255) / 256, 256, 0, stream>>>(deg, dinv);

    // scan: per-bucket sums/bases (reused by csort) + per-node offsets
    k_bsum<<<NBLK, 256, 0, stream>>>(deg, bsum);
    k_bscan<<<1, 512, 0, stream>>>(bsum, bbase, gcur);
    k_chunkscan<<<NBLK, 256, 0, stream>>>(deg, bbase, offs);

    // two-phase CSR build
    k_csort<<<NCB, 256, 0, stream>>>(esrc, edst, gcur, pairbuf);
    k_place<<<NBLK, 256, 0, stream>>>(pairbuf, bbase, offs, csr);

    // weight transpose+cast (tiny)
    k_wt<<<64, 256, 0, stream>>>(W1, Wt1, 128);
    k_wt<<<32, 256, 0, stream>>>(W2, Wt2, 64);

    const int MMB = (NN + 63) / 64;
    k_mm_mfma<128, false><<<MMB, 256, 0, stream>>>(x, Wt1, dinv, G1);
    k_agg_relu128<<<(NN + 3) / 4, 256, 0, stream>>>(G1, csr, offs, dinv, b1, B);
    k_mm_mfma<64, true><<<MMB, 256, 0, stream>>>(B, Wt2, dinv, G2);
    k_agg64<<<(NN + 3) / 4, 256, 0, stream>>>(G2, csr, offs, dinv, b2, AGG2);

    k_pool<<<NG, 256, 0, stream>>>(AGG2, batch, (float*)d_out);
}